// Round 12
// baseline (332.097 us; speedup 1.0000x reference)
//
#include <hip/hip_runtime.h>

#define E_EDGES 65536
#define NB 4096
#define DD 1536
#define CAP 96

typedef unsigned short u16;
typedef __bf16 bf16x8 __attribute__((ext_vector_type(8)));
typedef float f32x4 __attribute__((ext_vector_type(4)));

#define AS1(p) ((const __attribute__((address_space(1))) void*)(p))
#define AS3(p) ((__attribute__((address_space(3))) void*)(p))

#define BAR() do { __builtin_amdgcn_s_barrier(); asm volatile("" ::: "memory"); } while (0)
#define VMCNT0() asm volatile("s_waitcnt vmcnt(0)" ::: "memory")

__device__ __forceinline__ u16 f2bf(float f) {
    unsigned u = __float_as_uint(f);
    u += 0x7fffu + ((u >> 16) & 1u);   // round-to-nearest-even
    return (u16)(u >> 16);
}

// ---------------- prep: all weight transposes + edge bucketing, one launch ----------------

__global__ __launch_bounds__(256) void prep_kernel(
    const float* __restrict__ w0, const float* __restrict__ w1,
    const float* __restrict__ w2, const float* __restrict__ w3,
    const float* __restrict__ w4, const float* __restrict__ w5,
    u16* __restrict__ Wjt, u16* __restrict__ Wrt,
    u16* __restrict__ W1t, u16* __restrict__ W2t,
    const int* __restrict__ sj, const int* __restrict__ dj,
    const int* __restrict__ sr, const int* __restrict__ dr,
    int* __restrict__ cnt, int* __restrict__ bkt) {
    int bid = blockIdx.x;
    if (bid >= 10880) {
        int b2 = bid - 10880;            // 0..511
        int rel = b2 >> 8;
        int e = (b2 & 255) * 256 + threadIdx.x;
        int s = rel ? sr[e] : sj[e];
        int d = rel ? dr[e] : dj[e];
        int slot = rel * NB + d;
        int pos = atomicAdd(&cnt[slot], 1);
        if (pos < CAP) bkt[(size_t)slot * CAP + pos] = s;
        return;
    }
    const float* in; u16* out; int N, ldo, k0, nbx;
    if (bid < 9216) {
        int m = bid / 2304;
        bid = bid % 2304;
        in = (m == 0) ? w0 : (m == 1) ? w1 : (m == 2) ? w2 : w3;
        out = (m < 2) ? Wjt : Wrt;
        N = 1536; ldo = 3072; k0 = (m & 1) ? DD : 0; nbx = 48;
    } else if (bid < 10752) {
        bid -= 9216;
        in = w4; out = W1t; N = 512; ldo = 3072; k0 = 0; nbx = 16;
    } else {
        bid -= 10752;
        in = w5; out = W2t; N = 256; ldo = 512; k0 = 0; nbx = 8;
    }
    int bx = (bid % nbx) * 32;
    int by = (bid / nbx) * 32;
    __shared__ float tile[32][33];
    int tx = threadIdx.x & 31, ty = threadIdx.x >> 5;
#pragma unroll
    for (int i = 0; i < 4; ++i)
        tile[ty + i * 8][tx] = in[(size_t)(by + ty + i * 8) * N + bx + tx];
    __syncthreads();
#pragma unroll
    for (int i = 0; i < 4; ++i) {
        int n = bx + ty + i * 8;
        int k = by + tx;
        out[(size_t)n * ldo + k0 + k] = f2bf(tile[tx][ty + i * 8]);
    }
}

// ---------------- agg (segment-sum) + x_dst convert, fused per dst row ----------------
// 2-way unrolled edge loop: two independent load/accumulate chains.

__global__ __launch_bounds__(128) void agg_cvt_kernel(
    const float* __restrict__ xskill, const float* __restrict__ xj, const float* __restrict__ xr,
    const int* __restrict__ bkt, const int* __restrict__ cnt,
    u16* __restrict__ Aj, u16* __restrict__ Ar) {
    int rel = blockIdx.y;
    int row = blockIdx.x;
    int t = threadIdx.x;
    const float* xd = (rel ? xr : xj) + (size_t)row * DD;
    u16* A = (rel ? Ar : Aj) + (size_t)row * (2 * DD);

    float4 v[3];
#pragma unroll
    for (int c = 0; c < 3; ++c) v[c] = *(const float4*)(xd + t * 4 + c * 512);
#pragma unroll
    for (int c = 0; c < 3; ++c) {
        ushort4 o = {f2bf(v[c].x), f2bf(v[c].y), f2bf(v[c].z), f2bf(v[c].w)};
        *(ushort4*)(A + DD + t * 4 + c * 512) = o;
    }

    int count = cnt[rel * NB + row];
    if (count > CAP) count = CAP;
    __shared__ int sidx[CAP];
    if (t < count) sidx[t] = bkt[(size_t)(rel * NB + row) * CAP + t];
    __syncthreads();

    float4 acc0[3] = {};
    float4 acc1[3] = {};
    int e = 0;
    for (; e + 2 <= count; e += 2) {
        const float* x0 = xskill + (size_t)sidx[e] * DD;
        const float* x1 = xskill + (size_t)sidx[e + 1] * DD;
        float4 u0[3], u1[3];
#pragma unroll
        for (int c = 0; c < 3; ++c) u0[c] = *(const float4*)(x0 + t * 4 + c * 512);
#pragma unroll
        for (int c = 0; c < 3; ++c) u1[c] = *(const float4*)(x1 + t * 4 + c * 512);
#pragma unroll
        for (int c = 0; c < 3; ++c) {
            acc0[c].x += u0[c].x; acc0[c].y += u0[c].y; acc0[c].z += u0[c].z; acc0[c].w += u0[c].w;
            acc1[c].x += u1[c].x; acc1[c].y += u1[c].y; acc1[c].z += u1[c].z; acc1[c].w += u1[c].w;
        }
    }
    if (e < count) {
        const float* x0 = xskill + (size_t)sidx[e] * DD;
#pragma unroll
        for (int c = 0; c < 3; ++c) {
            float4 u = *(const float4*)(x0 + t * 4 + c * 512);
            acc0[c].x += u.x; acc0[c].y += u.y; acc0[c].z += u.z; acc0[c].w += u.w;
        }
    }
#pragma unroll
    for (int c = 0; c < 3; ++c) {
        acc0[c].x += acc1[c].x; acc0[c].y += acc1[c].y;
        acc0[c].z += acc1[c].z; acc0[c].w += acc1[c].w;
    }
#pragma unroll
    for (int c = 0; c < 3; ++c) {
        ushort4 o = {f2bf(acc0[c].x), f2bf(acc0[c].y), f2bf(acc0[c].z), f2bf(acc0[c].w)};
        *(ushort4*)(A + t * 4 + c * 512) = o;
    }
}

// ---------------- conv GEMM: 128x192 tile, BK=64, 4 waves, 2 blocks/CU ----------------
// Grid (32, 8, 2) = 512 blocks = 2/CU: the vmcnt(0)+barrier drain of one block is
// hidden by the co-resident block's compute (m114 inter-block overlap).
// LDS 80 KB/block (2 x 40 KB buffers) -> exactly 160 KB/CU at 2 blocks.
// LDS XOR-swizzle: LDS[r][c] holds global k = c ^ ((r&7)<<3) (u16 units);
// staging keeps LDS linear (global_load_lds) and pre-swizzles the GLOBAL source.

__global__ __launch_bounds__(256, 2) void conv_gemm(
    const u16* __restrict__ Aj, const u16* __restrict__ Wjt, const float* __restrict__ bj,
    const u16* __restrict__ Ar, const u16* __restrict__ Wrt, const float* __restrict__ br,
    u16* __restrict__ C) {
    constexpr int K = 3072, NT = K / 64, LDC = 3072;
    // per buf (u16): A [128][64] at +0 (8192), B [192][64] at +8192 (12288)
    constexpr int BUF = 20480;
    __shared__ u16 lds[2 * BUF];  // 80 KiB
    int tid = threadIdx.x;
    int lane = tid & 63;
    int w = tid >> 6;             // 0..3

    // XCD swizzle: each XCD owns all 32 m-tiles of ONE 192-col n-panel
    // (B panel 1.18 MB x 2 relations = 2.36 MB, L2-resident per XCD).
    int p = blockIdx.y * 32 + blockIdx.x;        // 0..255
    int lg = (p & 7) * 32 + (p >> 3);
    long bm = (long)(lg & 31) * 128;
    long bn = (long)(lg >> 5) * 192;

    const u16* A; const u16* Bt; const float* bias; long cofs;
    if (blockIdx.z) { A = Ar; Bt = Wrt; bias = br; cofs = DD; }
    else            { A = Aj; Bt = Wjt; bias = bj; cofs = 0;  }

    int wm = (w >> 1) * 64;    // wave M offset (0 or 64)
    int wn = (w & 1) * 96;     // wave N offset (0 or 96)

    // staging: group g covers rows 8g..8g+7; wave-uniform LDS base + HW lane*16
    const int srow = lane >> 3;
    const int skf = ((lane & 7) * 8) ^ ((lane >> 3) << 3);  // pre-swizzled global k

    auto stageA = [&](int b, long k0) {
#pragma unroll
        for (int i = 0; i < 4; ++i) {
            int g = i * 4 + w;               // 0..15 (128 rows)
            const u16* gp = A + (bm + g * 8 + srow) * (long)K + k0 + skf;
            __builtin_amdgcn_global_load_lds(AS1(gp), AS3(lds + b * BUF + g * 512), 16, 0, 0);
        }
    };
    auto stageB = [&](int b, long k0) {
#pragma unroll
        for (int i = 0; i < 6; ++i) {
            int g = i * 4 + w;               // 0..23 (192 rows)
            const u16* gp = Bt + (bn + g * 8 + srow) * (long)K + k0 + skf;
            __builtin_amdgcn_global_load_lds(AS1(gp), AS3(lds + b * BUF + 8192 + g * 512), 16, 0, 0);
        }
    };

    const int lrow = lane & 15;
    const int lko = (lane >> 4) * 8;
    const int rsw = (lane & 7) << 3;   // read-side XOR (row&7 == lane&7)

    auto ldA = [&](int b, int mi, int kk) -> bf16x8 {
        return *(const bf16x8*)(lds + b * BUF + (wm + mi * 16 + lrow) * 64 + ((kk + lko) ^ rsw));
    };
    auto ldB = [&](int b, int nj, int kk) -> bf16x8 {
        return *(const bf16x8*)(lds + b * BUF + 8192 + (wn + nj * 16 + lrow) * 64 + ((kk + lko) ^ rsw));
    };

    f32x4 acc[4][6] = {};

    stageA(0, 0); stageB(0, 0);

    for (int t = 0; t < NT; ++t) {
        int b = t & 1;
        VMCNT0();          // this wave's tile-t LDS writes complete
        BAR();             // all waves landed tile t; all done reading buf b^1
        if (t + 1 < NT) {  // block-uniform
            long k1 = (long)(t + 1) * 64;
            stageA(b ^ 1, k1); stageB(b ^ 1, k1);
        }
#pragma unroll
        for (int kk = 0; kk < 64; kk += 32) {
            bf16x8 bfr[6];
#pragma unroll
            for (int nj = 0; nj < 6; ++nj) bfr[nj] = ldB(b, nj, kk);
            bf16x8 af[4];
#pragma unroll
            for (int mi = 0; mi < 4; ++mi) af[mi] = ldA(b, mi, kk);
            __builtin_amdgcn_s_setprio(1);
#pragma unroll
            for (int mi = 0; mi < 4; ++mi)
#pragma unroll
                for (int nj = 0; nj < 6; ++nj)
                    acc[mi][nj] = __builtin_amdgcn_mfma_f32_16x16x32_bf16(af[mi], bfr[nj], acc[mi][nj], 0, 0, 0);
            __builtin_amdgcn_s_setprio(0);
        }
    }

    // epilogue: C/D frag mapping col=lane&15, row=(lane>>4)*4+reg
    int rb = (lane >> 4) * 4, cl = lane & 15;
#pragma unroll
    for (int mi = 0; mi < 4; ++mi)
#pragma unroll
        for (int nj = 0; nj < 6; ++nj) {
            long row = bm + wm + mi * 16 + rb;
            long col = bn + wn + nj * 16 + cl;
            float bb = bias[col];
#pragma unroll
            for (int r = 0; r < 4; ++r) {
                float v = fmaxf(acc[mi][nj][r] + bb, 0.f);
                C[(row + r) * (long)LDC + cofs + col] = f2bf(v);
            }
        }
}

// ---------------- 2-phase bf16 MFMA GEMM (mlp1/mlp2): C = relu(A @ Bt^T + bias) ----------------

template <int BM, bool OUT_BF16>
__global__ __launch_bounds__(256) void gemm_bias_relu(
    const u16* __restrict__ A, const u16* __restrict__ Bt, const float* __restrict__ bias,
    void* __restrict__ C, int K, int ldc) {
    constexpr int BK = 64;
    constexpr int MI = BM / 32;
    constexpr int NITER = (BM + 128) / 32;
    __shared__ u16 lA[BM * BK];
    __shared__ u16 lB[128 * BK];
    int tid = threadIdx.x;
    int lane = tid & 63;
    int w = tid >> 6;
    long bm = (long)blockIdx.x * BM;
    long bn = (long)blockIdx.y * 128;
    int wm = (w >> 1) * (BM / 2), wn = (w & 1) * 64;
    f32x4 acc[MI][4] = {};
    const int lrow = lane & 15;
    const int lko = (lane >> 4) * 8;

    for (int k0 = 0; k0 < K; k0 += BK) {
#pragma unroll
        for (int i = 0; i < NITER; ++i) {
            int chunk = i * 256 + tid;
            int row = chunk >> 3, kc = chunk & 7;
            if (row < BM) {
                const u16* g = A + (bm + row) * (long)K + k0 + kc * 8;
                __builtin_amdgcn_global_load_lds(AS1(g), AS3((char*)lA + i * 4096 + w * 1024), 16, 0, 0);
            } else {
                const u16* g = Bt + (bn + row - BM) * (long)K + k0 + kc * 8;
                __builtin_amdgcn_global_load_lds(AS1(g), AS3((char*)lB + i * 4096 + w * 1024 - BM * 128), 16, 0, 0);
            }
        }
        __syncthreads();
#pragma unroll
        for (int kk = 0; kk < BK; kk += 32) {
            bf16x8 af[MI], bfr[4];
#pragma unroll
            for (int i = 0; i < MI; ++i)
                af[i] = *(const bf16x8*)(lA + (wm + i * 16 + lrow) * BK + kk + lko);
#pragma unroll
            for (int j = 0; j < 4; ++j)
                bfr[j] = *(const bf16x8*)(lB + (wn + j * 16 + lrow) * BK + kk + lko);
#pragma unroll
            for (int i = 0; i < MI; ++i)
#pragma unroll
                for (int j = 0; j < 4; ++j)
                    acc[i][j] = __builtin_amdgcn_mfma_f32_16x16x32_bf16(af[i], bfr[j], acc[i][j], 0, 0, 0);
        }
        __syncthreads();
    }

    int rb = (lane >> 4) * 4, cl = lane & 15;
#pragma unroll
    for (int i = 0; i < MI; ++i)
#pragma unroll
        for (int j = 0; j < 4; ++j) {
            long row = bm + wm + i * 16 + rb;
            long col = bn + wn + j * 16 + cl;
            float b = bias[col];
#pragma unroll
            for (int r = 0; r < 4; ++r) {
                float v = fmaxf(acc[i][j][r] + b, 0.f);
                long o = (row + r) * (long)ldc + col;
                if (OUT_BF16)
                    ((u16*)C)[o] = f2bf(v);
                else
                    ((float*)C)[o] = v;
            }
        }
}

// ---------------- layers 3+4 fused (fp32 VALU): W3 staged in LDS, 4 waves x 4 rows ----------------

__global__ __launch_bounds__(256) void l34_kernel(
    const float* __restrict__ h2, const float* __restrict__ W3, const float* __restrict__ b3,
    const float* __restrict__ W4, const float* __restrict__ b4, float* __restrict__ out) {
    __shared__ float W3s[256 * 64];   // 64 KB
    __shared__ float hbuf[4][256];    // per-wave h2 row
    int tid = threadIdx.x;
#pragma unroll
    for (int i = 0; i < 16; ++i)
        ((float4*)W3s)[tid + i * 256] = ((const float4*)W3)[tid + i * 256];
    __syncthreads();
    int w = tid >> 6, t = tid & 63;
    float w4t = W4[t];
    float b3t = b3[t];
    float b40 = b4[0];
    for (int rr = 0; rr < 4; ++rr) {
        int row = blockIdx.x * 16 + w * 4 + rr;
        ((float4*)hbuf[w])[t] = ((const float4*)(h2 + (size_t)row * 256))[t];
        float acc = b3t;
#pragma unroll 8
        for (int k = 0; k < 256; ++k) acc = fmaf(hbuf[w][k], W3s[k * 64 + t], acc);
        acc = fmaxf(acc, 0.f);
        float s = acc * w4t;
#pragma unroll
        for (int o = 32; o > 0; o >>= 1) s += __shfl_down(s, o);
        if (t == 0) out[row] = s + b40;
    }
}

// ---------------- launch ----------------

extern "C" void kernel_launch(void* const* d_in, const int* in_sizes, int n_in,
                              void* d_out, int out_size, void* d_ws, size_t ws_size,
                              hipStream_t stream) {
    (void)in_sizes; (void)n_in; (void)out_size; (void)ws_size;
    const float* x_skill  = (const float*)d_in[0];
    const float* x_job    = (const float*)d_in[1];
    const float* x_resume = (const float*)d_in[2];
    const int* src_sj = (const int*)d_in[3];
    const int* dst_sj = (const int*)d_in[4];
    const int* src_sr = (const int*)d_in[5];
    const int* dst_sr = (const int*)d_in[6];
    const float* W_rel_j  = (const float*)d_in[7];
    const float* b_rel_j  = (const float*)d_in[8];
    const float* W_root_j = (const float*)d_in[9];
    const float* W_rel_r  = (const float*)d_in[10];
    const float* b_rel_r  = (const float*)d_in[11];
    const float* W_root_r = (const float*)d_in[12];
    const float* W1 = (const float*)d_in[13];
    const float* b1 = (const float*)d_in[14];
    const float* W2 = (const float*)d_in[15];
    const float* b2 = (const float*)d_in[16];
    const float* W3 = (const float*)d_in[17];
    const float* b3 = (const float*)d_in[18];
    const float* W4 = (const float*)d_in[19];
    const float* b4 = (const float*)d_in[20];
    float* out = (float*)d_out;

    char* p = (char*)d_ws;
    auto alloc = [&](size_t bytes) -> char* {
        char* r = p;
        p += (bytes + 255) & ~(size_t)255;
        return r;
    };
    int* cnt = (int*)alloc(2 * NB * 4);
    int* bkt = (int*)alloc((size_t)2 * NB * CAP * 4);
    u16* Aj   = (u16*)alloc((size_t)NB * 2 * DD * 2);
    u16* Ar   = (u16*)alloc((size_t)NB * 2 * DD * 2);
    u16* Wjt  = (u16*)alloc((size_t)DD * 2 * DD * 2);
    u16* Wrt  = (u16*)alloc((size_t)DD * 2 * DD * 2);
    u16* W1t  = (u16*)alloc((size_t)512 * 3072 * 2);
    u16* W2t  = (u16*)alloc((size_t)256 * 512 * 2);
    u16* hcat = (u16*)alloc((size_t)NB * 3072 * 2);
    u16* h1   = (u16*)alloc((size_t)NB * 512 * 2);
    float* h2 = (float*)alloc((size_t)NB * 256 * 4);

    hipMemsetAsync(cnt, 0, 2 * NB * 4, stream);
    // weight transposes + edge bucketing fused
    prep_kernel<<<11392, 256, 0, stream>>>(W_rel_j, W_root_j, W_rel_r, W_root_r, W1, W2,
                                           Wjt, Wrt, W1t, W2t,
                                           src_sj, dst_sj, src_sr, dst_sr, cnt, bkt);
    agg_cvt_kernel<<<dim3(NB, 2), 128, 0, stream>>>(x_skill, x_job, x_resume, bkt, cnt, Aj, Ar);

    // both convs: hcat[:, z*DD : z*DD+DD] = relu([agg|x] @ W + b), 128x192 tiles, 512 blocks (2/CU)
    conv_gemm<<<dim3(32, 8, 2), 256, 0, stream>>>(Aj, Wjt, b_rel_j, Ar, Wrt, b_rel_r, hcat);
    // mlp1: h1 = relu(hcat @ W1 + b1)
    gemm_bias_relu<64, true><<<dim3(NB / 64, 512 / 128), 256, 0, stream>>>(hcat, W1t, b1, h1, 3072, 512);
    // mlp2: h2 = relu(h1 @ W2 + b2), fp32 out
    gemm_bias_relu<64, false><<<dim3(NB / 64, 256 / 128), 256, 0, stream>>>(h1, W2t, b2, h2, 512, 256);
    // layers 3+4
    l34_kernel<<<NB / 16, 256, 0, stream>>>(h2, W3, b3, W4, b4, out);
}

// Round 13
// 322.218 us; speedup vs baseline: 1.0307x; 1.0307x over previous
//
#include <hip/hip_runtime.h>

#define E_EDGES 65536
#define NB 4096
#define DD 1536
#define CAP 96

typedef unsigned short u16;
typedef __bf16 bf16x8 __attribute__((ext_vector_type(8)));
typedef float f32x4 __attribute__((ext_vector_type(4)));

#define AS1(p) ((const __attribute__((address_space(1))) void*)(p))
#define AS3(p) ((__attribute__((address_space(3))) void*)(p))

#define BAR() do { __builtin_amdgcn_s_barrier(); asm volatile("" ::: "memory"); } while (0)
#define VMCNT0() asm volatile("s_waitcnt vmcnt(0)" ::: "memory")

__device__ __forceinline__ u16 f2bf(float f) {
    unsigned u = __float_as_uint(f);
    u += 0x7fffu + ((u >> 16) & 1u);   // round-to-nearest-even
    return (u16)(u >> 16);
}

// ---------------- prep: all weight transposes + edge bucketing, one launch ----------------

__global__ __launch_bounds__(256) void prep_kernel(
    const float* __restrict__ w0, const float* __restrict__ w1,
    const float* __restrict__ w2, const float* __restrict__ w3,
    const float* __restrict__ w4, const float* __restrict__ w5,
    u16* __restrict__ Wjt, u16* __restrict__ Wrt,
    u16* __restrict__ W1t, u16* __restrict__ W2t,
    const int* __restrict__ sj, const int* __restrict__ dj,
    const int* __restrict__ sr, const int* __restrict__ dr,
    int* __restrict__ cnt, int* __restrict__ bkt) {
    int bid = blockIdx.x;
    if (bid >= 10880) {
        int b2 = bid - 10880;            // 0..511
        int rel = b2 >> 8;
        int e = (b2 & 255) * 256 + threadIdx.x;
        int s = rel ? sr[e] : sj[e];
        int d = rel ? dr[e] : dj[e];
        int slot = rel * NB + d;
        int pos = atomicAdd(&cnt[slot], 1);
        if (pos < CAP) bkt[(size_t)slot * CAP + pos] = s;
        return;
    }
    const float* in; u16* out; int N, ldo, k0, nbx;
    if (bid < 9216) {
        int m = bid / 2304;
        bid = bid % 2304;
        in = (m == 0) ? w0 : (m == 1) ? w1 : (m == 2) ? w2 : w3;
        out = (m < 2) ? Wjt : Wrt;
        N = 1536; ldo = 3072; k0 = (m & 1) ? DD : 0; nbx = 48;
    } else if (bid < 10752) {
        bid -= 9216;
        in = w4; out = W1t; N = 512; ldo = 3072; k0 = 0; nbx = 16;
    } else {
        bid -= 10752;
        in = w5; out = W2t; N = 256; ldo = 512; k0 = 0; nbx = 8;
    }
    int bx = (bid % nbx) * 32;
    int by = (bid / nbx) * 32;
    __shared__ float tile[32][33];
    int tx = threadIdx.x & 31, ty = threadIdx.x >> 5;
#pragma unroll
    for (int i = 0; i < 4; ++i)
        tile[ty + i * 8][tx] = in[(size_t)(by + ty + i * 8) * N + bx + tx];
    __syncthreads();
#pragma unroll
    for (int i = 0; i < 4; ++i) {
        int n = bx + ty + i * 8;
        int k = by + tx;
        out[(size_t)n * ldo + k0 + k] = f2bf(tile[tx][ty + i * 8]);
    }
}

// ---------------- agg (segment-sum) + x_dst convert, fused per dst row ----------------
// 2-way unrolled edge loop: two independent load/accumulate chains.

__global__ __launch_bounds__(128) void agg_cvt_kernel(
    const float* __restrict__ xskill, const float* __restrict__ xj, const float* __restrict__ xr,
    const int* __restrict__ bkt, const int* __restrict__ cnt,
    u16* __restrict__ Aj, u16* __restrict__ Ar) {
    int rel = blockIdx.y;
    int row = blockIdx.x;
    int t = threadIdx.x;
    const float* xd = (rel ? xr : xj) + (size_t)row * DD;
    u16* A = (rel ? Ar : Aj) + (size_t)row * (2 * DD);

    float4 v[3];
#pragma unroll
    for (int c = 0; c < 3; ++c) v[c] = *(const float4*)(xd + t * 4 + c * 512);
#pragma unroll
    for (int c = 0; c < 3; ++c) {
        ushort4 o = {f2bf(v[c].x), f2bf(v[c].y), f2bf(v[c].z), f2bf(v[c].w)};
        *(ushort4*)(A + DD + t * 4 + c * 512) = o;
    }

    int count = cnt[rel * NB + row];
    if (count > CAP) count = CAP;
    __shared__ int sidx[CAP];
    if (t < count) sidx[t] = bkt[(size_t)(rel * NB + row) * CAP + t];
    __syncthreads();

    float4 acc0[3] = {};
    float4 acc1[3] = {};
    int e = 0;
    for (; e + 2 <= count; e += 2) {
        const float* x0 = xskill + (size_t)sidx[e] * DD;
        const float* x1 = xskill + (size_t)sidx[e + 1] * DD;
        float4 u0[3], u1[3];
#pragma unroll
        for (int c = 0; c < 3; ++c) u0[c] = *(const float4*)(x0 + t * 4 + c * 512);
#pragma unroll
        for (int c = 0; c < 3; ++c) u1[c] = *(const float4*)(x1 + t * 4 + c * 512);
#pragma unroll
        for (int c = 0; c < 3; ++c) {
            acc0[c].x += u0[c].x; acc0[c].y += u0[c].y; acc0[c].z += u0[c].z; acc0[c].w += u0[c].w;
            acc1[c].x += u1[c].x; acc1[c].y += u1[c].y; acc1[c].z += u1[c].z; acc1[c].w += u1[c].w;
        }
    }
    if (e < count) {
        const float* x0 = xskill + (size_t)sidx[e] * DD;
#pragma unroll
        for (int c = 0; c < 3; ++c) {
            float4 u = *(const float4*)(x0 + t * 4 + c * 512);
            acc0[c].x += u.x; acc0[c].y += u.y; acc0[c].z += u.z; acc0[c].w += u.w;
        }
    }
#pragma unroll
    for (int c = 0; c < 3; ++c) {
        acc0[c].x += acc1[c].x; acc0[c].y += acc1[c].y;
        acc0[c].z += acc1[c].z; acc0[c].w += acc1[c].w;
    }
#pragma unroll
    for (int c = 0; c < 3; ++c) {
        ushort4 o = {f2bf(acc0[c].x), f2bf(acc0[c].y), f2bf(acc0[c].z), f2bf(acc0[c].w)};
        *(ushort4*)(A + t * 4 + c * 512) = o;
    }
}

// ---------------- conv GEMM: 256x192 tile, BK=64, 8 waves, full-tile prefetch ----------------
// Flat grid 256 blocks = 1/CU, all concurrent. XCD x (=P&7) owns m-tiles {2x,2x+1}
// across ALL 8 bn panels and BOTH relations: the 8 blocks sharing an A-slab are
// co-XCD (A fetched ~once chip-wide, L2-resident 6.3MB/XCD); B streams via L3.
// One vmcnt(0)+barrier per K-tile. LDS XOR-swizzle: LDS[r][c] holds global
// k = c ^ ((r&7)<<3); staging pre-swizzles the GLOBAL source, LDS stays linear.

__global__ __launch_bounds__(512, 2) void conv_gemm(
    const u16* __restrict__ Aj, const u16* __restrict__ Wjt, const float* __restrict__ bj,
    const u16* __restrict__ Ar, const u16* __restrict__ Wrt, const float* __restrict__ br,
    u16* __restrict__ C) {
    constexpr int K = 3072, NT = K / 64, LDC = 3072;
    constexpr int BUF = 28672;
    __shared__ u16 lds[2 * BUF];  // 112 KiB
    int tid = threadIdx.x;
    int lane = tid & 63;
    int w = tid >> 6;

    // XCD-ownership remap (bijective): P -> (rel, bm, bn)
    int P = blockIdx.x;              // 0..255
    int x = P & 7;                   // XCD
    int q = P >> 3;                  // 0..31
    int rel = q >> 4;                // 16 blocks rel0, 16 rel1 per XCD
    int qq = q & 15;
    long bm = (long)(2 * x + (qq & 1)) * 256;
    long bn = (long)(qq >> 1) * 192;

    const u16* A; const u16* Bt; const float* bias; long cofs;
    if (rel) { A = Ar; Bt = Wrt; bias = br; cofs = DD; }
    else     { A = Aj; Bt = Wjt; bias = bj; cofs = 0;  }

    int wm = (w >> 2) * 128;
    int wn = (w & 3) * 48;

    const int srow = lane >> 3;
    const int skf = ((lane & 7) * 8) ^ ((lane >> 3) << 3);  // pre-swizzled global k

    auto stageA = [&](int b, long k0) {
#pragma unroll
        for (int i = 0; i < 4; ++i) {
            int g = i * 8 + w;
            const u16* gp = A + (bm + g * 8 + srow) * (long)K + k0 + skf;
            __builtin_amdgcn_global_load_lds(AS1(gp), AS3(lds + b * BUF + g * 512), 16, 0, 0);
        }
    };
    auto stageB = [&](int b, long k0) {
#pragma unroll
        for (int i = 0; i < 3; ++i) {
            int g = i * 8 + w;
            const u16* gp = Bt + (bn + g * 8 + srow) * (long)K + k0 + skf;
            __builtin_amdgcn_global_load_lds(AS1(gp), AS3(lds + b * BUF + 16384 + g * 512), 16, 0, 0);
        }
    };

    const int lrow = lane & 15;
    const int lko = (lane >> 4) * 8;
    const int rsw = (lane & 7) << 3;

    auto ldA = [&](int b, int mi, int kk) -> bf16x8 {
        return *(const bf16x8*)(lds + b * BUF + (wm + mi * 16 + lrow) * 64 + ((kk + lko) ^ rsw));
    };
    auto ldB = [&](int b, int nj, int kk) -> bf16x8 {
        return *(const bf16x8*)(lds + b * BUF + 16384 + (wn + nj * 16 + lrow) * 64 + ((kk + lko) ^ rsw));
    };

    f32x4 acc[8][3] = {};

    stageA(0, 0); stageB(0, 0);

    for (int t = 0; t < NT; ++t) {
        int b = t & 1;
        VMCNT0();
        BAR();
        if (t + 1 < NT) {
            long k1 = (long)(t + 1) * 64;
            stageA(b ^ 1, k1); stageB(b ^ 1, k1);
        }
#pragma unroll
        for (int kk = 0; kk < 64; kk += 32) {
            bf16x8 bfr[3];
#pragma unroll
            for (int nj = 0; nj < 3; ++nj) bfr[nj] = ldB(b, nj, kk);
#pragma unroll
            for (int h = 0; h < 2; ++h) {
                bf16x8 af[4];
#pragma unroll
                for (int mi = 0; mi < 4; ++mi) af[mi] = ldA(b, h * 4 + mi, kk);
                __builtin_amdgcn_s_setprio(1);
#pragma unroll
                for (int mi = 0; mi < 4; ++mi)
#pragma unroll
                    for (int nj = 0; nj < 3; ++nj)
                        acc[h * 4 + mi][nj] = __builtin_amdgcn_mfma_f32_16x16x32_bf16(af[mi], bfr[nj], acc[h * 4 + mi][nj], 0, 0, 0);
                __builtin_amdgcn_s_setprio(0);
            }
        }
    }

    int rb = (lane >> 4) * 4, cl = lane & 15;
#pragma unroll
    for (int mi = 0; mi < 8; ++mi)
#pragma unroll
        for (int nj = 0; nj < 3; ++nj) {
            long row = bm + wm + mi * 16 + rb;
            long col = bn + wn + nj * 16 + cl;
            float bb = bias[col];
#pragma unroll
            for (int r = 0; r < 4; ++r) {
                float v = fmaxf(acc[mi][nj][r] + bb, 0.f);
                C[(row + r) * (long)LDC + cofs + col] = f2bf(v);
            }
        }
}

// ---------------- 2-phase bf16 MFMA GEMM (mlp1/mlp2): C = relu(A @ Bt^T + bias) ----------------

template <int BM, bool OUT_BF16>
__global__ __launch_bounds__(256) void gemm_bias_relu(
    const u16* __restrict__ A, const u16* __restrict__ Bt, const float* __restrict__ bias,
    void* __restrict__ C, int K, int ldc) {
    constexpr int BK = 64;
    constexpr int MI = BM / 32;
    constexpr int NITER = (BM + 128) / 32;
    __shared__ u16 lA[BM * BK];
    __shared__ u16 lB[128 * BK];
    int tid = threadIdx.x;
    int lane = tid & 63;
    int w = tid >> 6;
    long bm = (long)blockIdx.x * BM;
    long bn = (long)blockIdx.y * 128;
    int wm = (w >> 1) * (BM / 2), wn = (w & 1) * 64;
    f32x4 acc[MI][4] = {};
    const int lrow = lane & 15;
    const int lko = (lane >> 4) * 8;

    for (int k0 = 0; k0 < K; k0 += BK) {
#pragma unroll
        for (int i = 0; i < NITER; ++i) {
            int chunk = i * 256 + tid;
            int row = chunk >> 3, kc = chunk & 7;
            if (row < BM) {
                const u16* g = A + (bm + row) * (long)K + k0 + kc * 8;
                __builtin_amdgcn_global_load_lds(AS1(g), AS3((char*)lA + i * 4096 + w * 1024), 16, 0, 0);
            } else {
                const u16* g = Bt + (bn + row - BM) * (long)K + k0 + kc * 8;
                __builtin_amdgcn_global_load_lds(AS1(g), AS3((char*)lB + i * 4096 + w * 1024 - BM * 128), 16, 0, 0);
            }
        }
        __syncthreads();
#pragma unroll
        for (int kk = 0; kk < BK; kk += 32) {
            bf16x8 af[MI], bfr[4];
#pragma unroll
            for (int i = 0; i < MI; ++i)
                af[i] = *(const bf16x8*)(lA + (wm + i * 16 + lrow) * BK + kk + lko);
#pragma unroll
            for (int j = 0; j < 4; ++j)
                bfr[j] = *(const bf16x8*)(lB + (wn + j * 16 + lrow) * BK + kk + lko);
#pragma unroll
            for (int i = 0; i < MI; ++i)
#pragma unroll
                for (int j = 0; j < 4; ++j)
                    acc[i][j] = __builtin_amdgcn_mfma_f32_16x16x32_bf16(af[i], bfr[j], acc[i][j], 0, 0, 0);
        }
        __syncthreads();
    }

    int rb = (lane >> 4) * 4, cl = lane & 15;
#pragma unroll
    for (int i = 0; i < MI; ++i)
#pragma unroll
        for (int j = 0; j < 4; ++j) {
            long row = bm + wm + i * 16 + rb;
            long col = bn + wn + j * 16 + cl;
            float b = bias[col];
#pragma unroll
            for (int r = 0; r < 4; ++r) {
                float v = fmaxf(acc[i][j][r] + b, 0.f);
                long o = (row + r) * (long)ldc + col;
                if (OUT_BF16)
                    ((u16*)C)[o] = f2bf(v);
                else
                    ((float*)C)[o] = v;
            }
        }
}

// ---------------- layers 3+4 fused (fp32 VALU): W3 staged in LDS, 4 waves x 4 rows ----------------

__global__ __launch_bounds__(256) void l34_kernel(
    const float* __restrict__ h2, const float* __restrict__ W3, const float* __restrict__ b3,
    const float* __restrict__ W4, const float* __restrict__ b4, float* __restrict__ out) {
    __shared__ float W3s[256 * 64];   // 64 KB
    __shared__ float hbuf[4][256];    // per-wave h2 row
    int tid = threadIdx.x;
#pragma unroll
    for (int i = 0; i < 16; ++i)
        ((float4*)W3s)[tid + i * 256] = ((const float4*)W3)[tid + i * 256];
    __syncthreads();
    int w = tid >> 6, t = tid & 63;
    float w4t = W4[t];
    float b3t = b3[t];
    float b40 = b4[0];
    for (int rr = 0; rr < 4; ++rr) {
        int row = blockIdx.x * 16 + w * 4 + rr;
        ((float4*)hbuf[w])[t] = ((const float4*)(h2 + (size_t)row * 256))[t];
        float acc = b3t;
#pragma unroll 8
        for (int k = 0; k < 256; ++k) acc = fmaf(hbuf[w][k], W3s[k * 64 + t], acc);
        acc = fmaxf(acc, 0.f);
        float s = acc * w4t;
#pragma unroll
        for (int o = 32; o > 0; o >>= 1) s += __shfl_down(s, o);
        if (t == 0) out[row] = s + b40;
    }
}

// ---------------- launch ----------------

extern "C" void kernel_launch(void* const* d_in, const int* in_sizes, int n_in,
                              void* d_out, int out_size, void* d_ws, size_t ws_size,
                              hipStream_t stream) {
    (void)in_sizes; (void)n_in; (void)out_size; (void)ws_size;
    const float* x_skill  = (const float*)d_in[0];
    const float* x_job    = (const float*)d_in[1];
    const float* x_resume = (const float*)d_in[2];
    const int* src_sj = (const int*)d_in[3];
    const int* dst_sj = (const int*)d_in[4];
    const int* src_sr = (const int*)d_in[5];
    const int* dst_sr = (const int*)d_in[6];
    const float* W_rel_j  = (const float*)d_in[7];
    const float* b_rel_j  = (const float*)d_in[8];
    const float* W_root_j = (const float*)d_in[9];
    const float* W_rel_r  = (const float*)d_in[10];
    const float* b_rel_r  = (const float*)d_in[11];
    const float* W_root_r = (const float*)d_in[12];
    const float* W1 = (const float*)d_in[13];
    const float* b1 = (const float*)d_in[14];
    const float* W2 = (const float*)d_in[15];
    const float* b2 = (const float*)d_in[16];
    const float* W3 = (const float*)d_in[17];
    const float* b3 = (const float*)d_in[18];
    const float* W4 = (const float*)d_in[19];
    const float* b4 = (const float*)d_in[20];
    float* out = (float*)d_out;

    char* p = (char*)d_ws;
    auto alloc = [&](size_t bytes) -> char* {
        char* r = p;
        p += (bytes + 255) & ~(size_t)255;
        return r;
    };
    int* cnt = (int*)alloc(2 * NB * 4);
    int* bkt = (int*)alloc((size_t)2 * NB * CAP * 4);
    u16* Aj   = (u16*)alloc((size_t)NB * 2 * DD * 2);
    u16* Ar   = (u16*)alloc((size_t)NB * 2 * DD * 2);
    u16* Wjt  = (u16*)alloc((size_t)DD * 2 * DD * 2);
    u16* Wrt  = (u16*)alloc((size_t)DD * 2 * DD * 2);
    u16* W1t  = (u16*)alloc((size_t)512 * 3072 * 2);
    u16* W2t  = (u16*)alloc((size_t)256 * 512 * 2);
    u16* hcat = (u16*)alloc((size_t)NB * 3072 * 2);
    u16* h1   = (u16*)alloc((size_t)NB * 512 * 2);
    float* h2 = (float*)alloc((size_t)NB * 256 * 4);

    hipMemsetAsync(cnt, 0, 2 * NB * 4, stream);
    // weight transposes + edge bucketing fused
    prep_kernel<<<11392, 256, 0, stream>>>(W_rel_j, W_root_j, W_rel_r, W_root_r, W1, W2,
                                           Wjt, Wrt, W1t, W2t,
                                           src_sj, dst_sj, src_sr, dst_sr, cnt, bkt);
    agg_cvt_kernel<<<dim3(NB, 2), 128, 0, stream>>>(x_skill, x_job, x_resume, bkt, cnt, Aj, Ar);

    // both convs: hcat = relu([agg|x] @ W + b), 256x192 tiles, flat 256 blocks, m-per-XCD map
    conv_gemm<<<256, 512, 0, stream>>>(Aj, Wjt, b_rel_j, Ar, Wrt, b_rel_r, hcat);
    // mlp1: h1 = relu(hcat @ W1 + b1)
    gemm_bias_relu<64, true><<<dim3(NB / 64, 512 / 128), 256, 0, stream>>>(hcat, W1t, b1, h1, 3072, 512);
    // mlp2: h2 = relu(h1 @ W2 + b2), fp32 out
    gemm_bias_relu<64, false><<<dim3(NB / 64, 256 / 128), 256, 0, stream>>>(h1, W2t, b2, h2, 512, 256);
    // layers 3+4
    l34_kernel<<<NB / 16, 256, 0, stream>>>(h2, W3, b3, W4, b4, out);
}